// Round 9
// baseline (938.951 us; speedup 1.0000x reference)
//
#include <hip/hip_runtime.h>

// PiecewiseSparseMLP: B=262144 rows, K=32 experts (10 -> 20 -> 1), distance-softmax gating.
// Round 9: R7's fully-unrolled MFMA structure (64 VGPR) + R8's improvements done right:
//  - LDS 25.9 KB (A-frags only for 20 valid hidden rows) + __launch_bounds__(256,6)
//    -> 6 blocks/CU, 24 waves/CU (R8's spill was the `unroll 1` dynamic-indexed gx[],
//    NOT the cap: R7's unrolled body needs only 64 VGPR < 84 cap).
//  - w2 read as float4 (8 ds_read_b128/pair vs 16 ds_read_b64) -> halves w2 LDS issue.
//  - gating MFMA emits -2*x.p directly (-2 baked into proto frags); pn2+xn2 fixup in
//    fp32 packed adds (pn2 in bf16 would cost ~7e-3 accuracy).
//  - gx pre-exchange + b2 fold kept, expert loop FULLY unrolled (static indices only).

#define KX 32
#define DIN 10
#define DH 20

typedef short bf16x8 __attribute__((ext_vector_type(8)));
typedef float f32x16 __attribute__((ext_vector_type(16)));
typedef float v2f    __attribute__((ext_vector_type(2)));

#define ZERO16 {0.f,0.f,0.f,0.f, 0.f,0.f,0.f,0.f, 0.f,0.f,0.f,0.f, 0.f,0.f,0.f,0.f}

__device__ inline unsigned short f2bf(float f) {   // fp32 -> bf16 RNE
    unsigned int u = __float_as_uint(f);
    unsigned int r = u + 0x7fffu + ((u >> 16) & 1u);
    return (unsigned short)(r >> 16);
}

union BFU { bf16x8 v; unsigned short s[8]; };

__global__ __launch_bounds__(256, 6) void moe_kernel(
    const float* __restrict__ x,      // [B,10]
    const float* __restrict__ W1,     // [32,20,10]
    const float* __restrict__ b1,     // [32,20]
    const float* __restrict__ W2,     // [32,1,20]
    const float* __restrict__ b2,     // [32]
    const float* __restrict__ proto,  // [32,10]
    float* __restrict__ out,          // [B]
    int B)
{
    __shared__ bf16x8 s_af[KX * 40];   // A-frags, valid hidden rows only (20 KB)
    __shared__ float  s_w2[KX * 32];   // W2 in C-layout order per half (4 KB)
    __shared__ bf16x8 s_pf[64];        // proto A-frag, -2*p baked (1 KB)
    __shared__ float  s_pn2c[32];      // ||proto||^2, C-layout order (fp32)
    __shared__ float  s_b2c[32];       // b2, C-layout order

    const int tid = threadIdx.x;

    // ---- build LDS tables ----
    for (int idx = tid; idx < KX * 40; idx += 256) {
        const int e = idx / 40, rem = idx - e * 40;
        const int hf = rem / 20, m = rem - hf * 20;
        BFU u;
#pragma unroll
        for (int j = 0; j < 8; ++j) {
            const int kk = hf * 8 + j;
            float v = 0.f;
            if (kk < DIN) v = W1[(e * DH + m) * DIN + kk];
            else if (kk == DIN) v = b1[e * DH + m];   // bias slot (x_ext[10]=1)
            u.s[j] = f2bf(v);
        }
        s_af[idx] = u.v;
    }
    for (int idx = tid; idx < KX * 32; idx += 256) {
        const int e = idx >> 5, rem = idx & 31;
        const int hf = rem >> 4, q = rem & 15;
        const int hid = (q & 3) + 8 * (q >> 2) + 4 * hf;
        s_w2[idx] = (hid < DH) ? W2[e * DH + hid] : 0.f;
    }
    if (tid < 64) {
        const int m = tid & 31, kb = (tid >> 5) * 8;
        BFU u;
#pragma unroll
        for (int j = 0; j < 8; ++j) {
            const int kk = kb + j;
            u.s[j] = f2bf(kk < DIN ? -2.f * proto[m * DIN + kk] : 0.f);
        }
        s_pf[tid] = u.v;
    }
    if (tid < 32) {
        const int hf = tid >> 4, q = tid & 15;
        const int p = (q & 3) + 8 * (q >> 2) + 4 * hf;
        float s = 0.f;
#pragma unroll
        for (int i = 0; i < DIN; ++i) { const float v = proto[p * DIN + i]; s = fmaf(v, v, s); }
        s_pn2c[tid] = s;
        s_b2c[tid] = b2[p];
    }
    __syncthreads();

    const int lane = tid & 63;
    const int wave = tid >> 6;
    const int half = lane >> 5;
    const int col  = lane & 31;

    const int row = (blockIdx.x * 4 + wave) * 32 + col;
    const int rr = (row < B) ? row : (B - 1);

    // ---- B-frag: x_ext[rr][half*8 .. +7]; slot 10 = 1.0 (bias) ----
    float xe[8];
    const float* xr = x + (size_t)rr * DIN;
    if (half == 0) {
#pragma unroll
        for (int i = 0; i < 4; ++i) {
            const float2 v = *(const float2*)(xr + 2 * i);
            xe[2 * i] = v.x; xe[2 * i + 1] = v.y;
        }
    } else {
        const float2 v = *(const float2*)(xr + 8);
        xe[0] = v.x; xe[1] = v.y; xe[2] = 1.f;
        xe[3] = 0.f; xe[4] = 0.f; xe[5] = 0.f; xe[6] = 0.f; xe[7] = 0.f;
    }
    BFU xu;
#pragma unroll
    for (int j = 0; j < 8; ++j) xu.s[j] = f2bf(xe[j]);
    const bf16x8 xfrag = xu.v;

    // ||x||^2 (fp32): half0 sums its 8, half1 only x[8],x[9]
    float part;
    if (half == 0) {
        part = 0.f;
#pragma unroll
        for (int j = 0; j < 8; ++j) part = fmaf(xe[j], xe[j], part);
    } else {
        part = fmaf(xe[0], xe[0], xe[1] * xe[1]);
    }
    const float xn2 = part + __shfl_xor(part, 32);

    // ---- gating MFMA: out = -2*x.p ; d2 = out + pn2 + xn2 (fp32 fixup) ----
    f32x16 zg = ZERO16;
    const f32x16 dotg = __builtin_amdgcn_mfma_f32_32x32x16_bf16(s_pf[lane], xfrag, zg, 0, 0, 0);

    float gate[16], gx[16];
    float dsum = 0.f, nsum = 0.f;
    {
        const float4* pn4 = (const float4*)(s_pn2c + half * 16);
        const float4* b24 = (const float4*)(s_b2c + half * 16);
        const v2f xnv = v2f{xn2, xn2};
#pragma unroll
        for (int i = 0; i < 4; ++i) {
            const float4 pn = pn4[i];
            const float4 bb = b24[i];
            v2f s2a = v2f{pn.x, pn.y} + xnv;
            v2f s2b = v2f{pn.z, pn.w} + xnv;
            v2f d2a = v2f{dotg[4 * i + 0], dotg[4 * i + 1]} + s2a;
            v2f d2b = v2f{dotg[4 * i + 2], dotg[4 * i + 3]} + s2b;
            d2a = __builtin_elementwise_max(d2a, v2f{0.f, 0.f});
            d2b = __builtin_elementwise_max(d2b, v2f{0.f, 0.f});
            const float g0 = __expf(-__fsqrt_rn(d2a.x));
            const float g1 = __expf(-__fsqrt_rn(d2a.y));
            const float g2 = __expf(-__fsqrt_rn(d2b.x));
            const float g3 = __expf(-__fsqrt_rn(d2b.y));
            gate[4 * i + 0] = g0; gate[4 * i + 1] = g1;
            gate[4 * i + 2] = g2; gate[4 * i + 3] = g3;
            dsum += (g0 + g1) + (g2 + g3);
            nsum = fmaf(g0, bb.x, nsum);
            nsum = fmaf(g1, bb.y, nsum);
            nsum = fmaf(g2, bb.z, nsum);
            nsum = fmaf(g3, bb.w, nsum);
        }
#pragma unroll
        for (int q = 0; q < 16; ++q) gx[q] = __shfl_xor(gate[q], 32);
    }

    // ---- expert loop: pairs (elo, elo+4), FULLY unrolled ----
    const int mrow = col;
#pragma unroll
    for (int j = 0; j < 16; ++j) {
        const int elo = (j & 3) + 8 * (j >> 2);
        const int ehi = elo + 4;

        bf16x8 alo = {0, 0, 0, 0, 0, 0, 0, 0};
        bf16x8 ahi = {0, 0, 0, 0, 0, 0, 0, 0};
        if (mrow < DH) {
            alo = s_af[elo * 40 + half * 20 + mrow];
            ahi = s_af[ehi * 40 + half * 20 + mrow];
        }
        f32x16 z0 = ZERO16, z1 = ZERO16;
        const f32x16 clo = __builtin_amdgcn_mfma_f32_32x32x16_bf16(alo, xfrag, z0, 0, 0, 0);
        const f32x16 chi = __builtin_amdgcn_mfma_f32_32x32x16_bf16(ahi, xfrag, z1, 0, 0, 0);

        const float4* w4lo = (const float4*)(s_w2 + elo * 32 + half * 16);
        const float4* w4hi = (const float4*)(s_w2 + ehi * 32 + half * 16);
        v2f plov = v2f{0.f, 0.f}, phiv = v2f{0.f, 0.f};
#pragma unroll
        for (int i = 0; i < 4; ++i) {
            const float4 wl = w4lo[i];
            const float4 wh = w4hi[i];
            v2f cl0 = __builtin_elementwise_max(v2f{clo[4 * i + 0], clo[4 * i + 1]}, v2f{0.f, 0.f});
            v2f cl1 = __builtin_elementwise_max(v2f{clo[4 * i + 2], clo[4 * i + 3]}, v2f{0.f, 0.f});
            v2f ch0 = __builtin_elementwise_max(v2f{chi[4 * i + 0], chi[4 * i + 1]}, v2f{0.f, 0.f});
            v2f ch1 = __builtin_elementwise_max(v2f{chi[4 * i + 2], chi[4 * i + 3]}, v2f{0.f, 0.f});
            plov = __builtin_elementwise_fma(cl0, v2f{wl.x, wl.y}, plov);
            plov = __builtin_elementwise_fma(cl1, v2f{wl.z, wl.w}, plov);
            phiv = __builtin_elementwise_fma(ch0, v2f{wh.x, wh.y}, phiv);
            phiv = __builtin_elementwise_fma(ch1, v2f{wh.z, wh.w}, phiv);
        }
        const float pplo = plov.x + plov.y;
        const float pphi = phiv.x + phiv.y;

        // half0 lane: own expert = elo (partial pplo); half1 lane: own = ehi (pphi)
        const float p_own = half ? pphi : pplo;
        const float p_oth = half ? pplo : pphi;
        nsum = fmaf(gate[j], p_own, nsum);
        nsum = fmaf(gx[j],   p_oth, nsum);
    }

    // ---- cross-half combine & write ----
    nsum += __shfl_xor(nsum, 32);
    dsum += __shfl_xor(dsum, 32);
    if (half == 0 && row < B) out[row] = nsum / dsum;
}

extern "C" void kernel_launch(void* const* d_in, const int* in_sizes, int n_in,
                              void* d_out, int out_size, void* d_ws, size_t ws_size,
                              hipStream_t stream) {
    const float* x     = (const float*)d_in[0];
    const float* W1    = (const float*)d_in[1];
    const float* b1    = (const float*)d_in[2];
    const float* W2    = (const float*)d_in[3];
    const float* b2    = (const float*)d_in[4];
    const float* proto = (const float*)d_in[5];
    float* out = (float*)d_out;

    const int B = out_size;            // D_OUT = 1
    const int rows_per_block = 4 * 32; // 4 waves x 1 tile x 32 rows
    const int grid = (B + rows_per_block - 1) / rows_per_block;
    hipLaunchKernelGGL(moe_kernel, dim3(grid), dim3(256), 0, stream,
                       x, W1, b1, W2, b2, proto, out, B);
}

// Round 10
// 107.658 us; speedup vs baseline: 8.7216x; 8.7216x over previous
//
#include <hip/hip_runtime.h>

// PiecewiseSparseMLP: B=262144 rows, K=32 experts (10 -> 20 -> 1), distance-softmax gating.
// Round 10: R7's known-good MFMA structure (64 VGPR, unroll 2, launch_bounds(256,4) ->
// 128-VGPR cap) with exactly three deltas:
//  (1) LDS 38.4 -> ~26 KB (A-frags stored only for 20 valid hidden rows) -> 6 blocks/CU;
//  (2) 1 tile/wave, grid=2048, so the freed residency is consumed;
//  (3) epilogue: w2 as float4 (b128) + packed pk_max/pk_fma (halves epilogue LDS+VALU).
// Spill lessons: R8 (`unroll 1` -> dynamic gate[] -> scratch) and R9 (full unroll under
// a tight 84-VGPR cap -> 2 GB scratch storm). unroll 2 + 128-cap is the proven point.

#define KX 32
#define DIN 10
#define DH 20

typedef short bf16x8 __attribute__((ext_vector_type(8)));
typedef float f32x16 __attribute__((ext_vector_type(16)));
typedef float v2f    __attribute__((ext_vector_type(2)));

#define ZERO16 {0.f,0.f,0.f,0.f, 0.f,0.f,0.f,0.f, 0.f,0.f,0.f,0.f, 0.f,0.f,0.f,0.f}

__device__ inline unsigned short f2bf(float f) {   // fp32 -> bf16 RNE
    unsigned int u = __float_as_uint(f);
    unsigned int r = u + 0x7fffu + ((u >> 16) & 1u);
    return (unsigned short)(r >> 16);
}

union BFU { bf16x8 v; unsigned short s[8]; };

__global__ __launch_bounds__(256, 4) void moe_kernel(
    const float* __restrict__ x,      // [B,10]
    const float* __restrict__ W1,     // [32,20,10]
    const float* __restrict__ b1,     // [32,20]
    const float* __restrict__ W2,     // [32,1,20]
    const float* __restrict__ b2,     // [32]
    const float* __restrict__ proto,  // [32,10]
    float* __restrict__ out,          // [B]
    int B)
{
    __shared__ bf16x8 s_af[KX * 40];   // A-frags, valid hidden rows only (20 KB)
    __shared__ float  s_w2[KX * 32];   // [e][half*16+reg] W2 in C-layout order (4 KB)
    __shared__ bf16x8 s_pf[64];        // proto A-frag (1 KB)
    __shared__ float  s_pn2[32];       // ||proto||^2 in [half*16+reg] order

    const int tid = threadIdx.x;

    // ---- build LDS tables ----
    for (int idx = tid; idx < KX * 40; idx += 256) {
        const int e = idx / 40, rem = idx - e * 40;
        const int hf = rem / 20, m = rem - hf * 20;
        BFU u;
#pragma unroll
        for (int j = 0; j < 8; ++j) {
            const int kk = hf * 8 + j;
            float v = 0.f;
            if (kk < DIN) v = W1[(e * DH + m) * DIN + kk];
            else if (kk == DIN) v = b1[e * DH + m];   // bias slot (x_ext[10]=1)
            u.s[j] = f2bf(v);
        }
        s_af[idx] = u.v;
    }
    for (int idx = tid; idx < KX * 32; idx += 256) {
        const int e = idx >> 5, rem = idx & 31;
        const int hf = rem >> 4, q = rem & 15;
        const int hid = (q & 3) + 8 * (q >> 2) + 4 * hf;
        s_w2[idx] = (hid < DH) ? W2[e * DH + hid] : 0.f;
    }
    if (tid < 64) {
        const int m = tid & 31, kb = (tid >> 5) * 8;
        BFU u;
#pragma unroll
        for (int j = 0; j < 8; ++j) {
            const int kk = kb + j;
            u.s[j] = f2bf(kk < DIN ? proto[m * DIN + kk] : 0.f);  // slot 10 = 0
        }
        s_pf[tid] = u.v;
    }
    if (tid < 32) {
        const int hf = tid >> 4, q = tid & 15;
        const int p = (q & 3) + 8 * (q >> 2) + 4 * hf;
        float s = 0.f;
#pragma unroll
        for (int i = 0; i < DIN; ++i) { const float v = proto[p * DIN + i]; s = fmaf(v, v, s); }
        s_pn2[tid] = s;
    }
    __syncthreads();

    const int lane = tid & 63;
    const int wave = tid >> 6;
    const int half = lane >> 5;
    const int col  = lane & 31;
    const bf16x8 pfrag = s_pf[lane];
    const float* pn2h = s_pn2 + half * 16;

    const int row = (blockIdx.x * 4 + wave) * 32 + col;
    const int rr = (row < B) ? row : (B - 1);

    // ---- B-frag: x_ext[rr][half*8 .. +7]; slot 10 = 1.0 (bias) ----
    float xe[8];
    const float* xr = x + (size_t)rr * DIN;
    if (half == 0) {
#pragma unroll
        for (int i = 0; i < 4; ++i) {
            const float2 v = *(const float2*)(xr + 2 * i);
            xe[2 * i] = v.x; xe[2 * i + 1] = v.y;
        }
    } else {
        const float2 v = *(const float2*)(xr + 8);
        xe[0] = v.x; xe[1] = v.y; xe[2] = 1.f;
        xe[3] = 0.f; xe[4] = 0.f; xe[5] = 0.f; xe[6] = 0.f; xe[7] = 0.f;
    }
    BFU xu;
#pragma unroll
    for (int j = 0; j < 8; ++j) xu.s[j] = f2bf(xe[j]);
    const bf16x8 xfrag = xu.v;

    // ||x||^2 (fp32): half0 sums its 8, half1 only x[8],x[9]
    float part;
    if (half == 0) {
        part = 0.f;
#pragma unroll
        for (int j = 0; j < 8; ++j) part = fmaf(xe[j], xe[j], part);
    } else {
        part = fmaf(xe[0], xe[0], xe[1] * xe[1]);
    }
    const float xn2 = part + __shfl_xor(part, 32);

    // ---- gating MFMA: dot[p, r] for all 32 protos ----
    f32x16 zg = ZERO16;
    const f32x16 dotg = __builtin_amdgcn_mfma_f32_32x32x16_bf16(pfrag, xfrag, zg, 0, 0, 0);

    float gate[16];
#pragma unroll
    for (int q = 0; q < 16; ++q) {
        float d2 = fmaf(dotg[q], -2.f, xn2 + pn2h[q]);
        d2 = fmaxf(d2, 0.f);
        gate[q] = __expf(-__fsqrt_rn(d2));
    }

    // ---- expert loop: pairs (elo, elo+4) across lane halves (R7 body, packed epilogue) ----
    const int mrow = col;
    float accn[16];
#pragma unroll 2
    for (int j = 0; j < 16; ++j) {
        const int elo = (j & 3) + 8 * (j >> 2);
        const int ehi = elo + 4;

        bf16x8 alo = {0, 0, 0, 0, 0, 0, 0, 0};
        bf16x8 ahi = {0, 0, 0, 0, 0, 0, 0, 0};
        if (mrow < DH) {
            alo = s_af[elo * 40 + half * 20 + mrow];
            ahi = s_af[ehi * 40 + half * 20 + mrow];
        }
        f32x16 z0 = ZERO16, z1 = ZERO16;
        const f32x16 clo = __builtin_amdgcn_mfma_f32_32x32x16_bf16(alo, xfrag, z0, 0, 0, 0);
        const f32x16 chi = __builtin_amdgcn_mfma_f32_32x32x16_bf16(ahi, xfrag, z1, 0, 0, 0);

        const float4* w4lo = (const float4*)(s_w2 + elo * 32 + half * 16);
        const float4* w4hi = (const float4*)(s_w2 + ehi * 32 + half * 16);
        v2f plov = v2f{0.f, 0.f}, phiv = v2f{0.f, 0.f};
#pragma unroll
        for (int i = 0; i < 4; ++i) {
            const float4 wl = w4lo[i];
            const float4 wh = w4hi[i];
            v2f cl0 = __builtin_elementwise_max(v2f{clo[4 * i + 0], clo[4 * i + 1]}, v2f{0.f, 0.f});
            v2f cl1 = __builtin_elementwise_max(v2f{clo[4 * i + 2], clo[4 * i + 3]}, v2f{0.f, 0.f});
            v2f ch0 = __builtin_elementwise_max(v2f{chi[4 * i + 0], chi[4 * i + 1]}, v2f{0.f, 0.f});
            v2f ch1 = __builtin_elementwise_max(v2f{chi[4 * i + 2], chi[4 * i + 3]}, v2f{0.f, 0.f});
            plov = __builtin_elementwise_fma(cl0, v2f{wl.x, wl.y}, plov);
            plov = __builtin_elementwise_fma(cl1, v2f{wl.z, wl.w}, plov);
            phiv = __builtin_elementwise_fma(ch0, v2f{wh.x, wh.y}, phiv);
            phiv = __builtin_elementwise_fma(ch1, v2f{wh.z, wh.w}, phiv);
        }
        const float pplo = plov.x + plov.y;
        const float pphi = phiv.x + phiv.y;
        const float plo = pplo + __shfl_xor(pplo, 32);
        const float phi = pphi + __shfl_xor(pphi, 32);
        const float pred = half ? (phi + b2[ehi]) : (plo + b2[elo]);
        accn[j] = gate[j] * pred;
    }

    // ---- finalize: sum over this half's 16 experts, then cross-half ----
    float nsum = 0.f, dsum = 0.f;
#pragma unroll
    for (int q = 0; q < 16; ++q) { nsum += accn[q]; dsum += gate[q]; }
    nsum += __shfl_xor(nsum, 32);
    dsum += __shfl_xor(dsum, 32);
    if (half == 0 && row < B) out[row] = nsum / dsum;
}

extern "C" void kernel_launch(void* const* d_in, const int* in_sizes, int n_in,
                              void* d_out, int out_size, void* d_ws, size_t ws_size,
                              hipStream_t stream) {
    const float* x     = (const float*)d_in[0];
    const float* W1    = (const float*)d_in[1];
    const float* b1    = (const float*)d_in[2];
    const float* W2    = (const float*)d_in[3];
    const float* b2    = (const float*)d_in[4];
    const float* proto = (const float*)d_in[5];
    float* out = (float*)d_out;

    const int B = out_size;            // D_OUT = 1
    const int rows_per_block = 4 * 32; // 4 waves x 1 tile x 32 rows
    const int grid = (B + rows_per_block - 1) / rows_per_block;
    hipLaunchKernelGGL(moe_kernel, dim3(grid), dim3(256), 0, stream,
                       x, W1, b1, W2, b2, proto, out, B);
}

// Round 11
// 101.876 us; speedup vs baseline: 9.2166x; 1.0568x over previous
//
#include <hip/hip_runtime.h>

// PiecewiseSparseMLP: B=262144 rows, K=32 experts (10 -> 20 -> 1), distance-softmax gating.
// Round 11: R10 base + two epilogue cuts:
//  (1) hidden->m remap ("C-reg compaction"): the 20 hidden units are placed at m-slots
//      that land in C-regs 0..9 for each lane half (half0: m in {0-3,8-11,16,17},
//      half1: {4-7,12-15,20,21}; h=(m&3)+4*(m>>3)+10*(m&4!=0)). Epilogue reads only
//      regs 0..11 (12-padded): 24 pk ops + 6 ds_read_b128 per pair vs 32 + 8.
//  (2) gx pre-exchange + b2 fold (no per-pair shuffles; b2 added in gating loop),
//      in the proven no-spill pattern (unroll 2, launch_bounds(256,4) -> cap 128).
// Spill lessons: R8 (`unroll 1` dynamic arrays) and R9 (tight 84 cap) both scratch-stormed;
// R7/R10 (unroll 2, cap 128) is the stable point — kept verbatim.

#define KX 32
#define DIN 10
#define DH 20

typedef short bf16x8 __attribute__((ext_vector_type(8)));
typedef float f32x16 __attribute__((ext_vector_type(16)));
typedef float v2f    __attribute__((ext_vector_type(2)));

#define ZERO16 {0.f,0.f,0.f,0.f, 0.f,0.f,0.f,0.f, 0.f,0.f,0.f,0.f, 0.f,0.f,0.f,0.f}

__device__ inline unsigned short f2bf(float f) {   // fp32 -> bf16 RNE
    unsigned int u = __float_as_uint(f);
    unsigned int r = u + 0x7fffu + ((u >> 16) & 1u);
    return (unsigned short)(r >> 16);
}

union BFU { bf16x8 v; unsigned short s[8]; };

__global__ __launch_bounds__(256, 4) void moe_kernel(
    const float* __restrict__ x,      // [B,10]
    const float* __restrict__ W1,     // [32,20,10]
    const float* __restrict__ b1,     // [32,20]
    const float* __restrict__ W2,     // [32,1,20]
    const float* __restrict__ b2,     // [32]
    const float* __restrict__ proto,  // [32,10]
    float* __restrict__ out,          // [B]
    int B)
{
    __shared__ bf16x8 s_af[KX * 40];   // A-frags: [e][kslice*20 + h] (20 KB)
    __shared__ float  s_w2[KX * 24];   // [e][half*12 + reg] W2 in compacted C-reg order (3 KB)
    __shared__ bf16x8 s_pf[64];        // proto A-frag (1 KB)
    __shared__ float  s_pn2[32];       // ||proto||^2 in [half*16+reg] order
    __shared__ float  s_b2c[32];       // b2 in [half*16+reg] order

    const int tid = threadIdx.x;

    // ---- build LDS tables ----
    for (int idx = tid; idx < KX * 40; idx += 256) {
        const int e = idx / 40, rem = idx - e * 40;
        const int ks = rem / 20, h = rem - ks * 20;   // k-slice, hidden index
        BFU u;
#pragma unroll
        for (int j = 0; j < 8; ++j) {
            const int kk = ks * 8 + j;
            float v = 0.f;
            if (kk < DIN) v = W1[(e * DH + h) * DIN + kk];
            else if (kk == DIN) v = b1[e * DH + h];   // bias slot (x_ext[10]=1)
            u.s[j] = f2bf(v);
        }
        s_af[idx] = u.v;
    }
    // W2 in compacted C-reg order: reg q of half hf -> m=(q&3)+8*(q>>2)+4*hf ->
    // h=(m&3)+4*(m>>3)+10*((m&4)?1:0); q=10,11 are pad (zero).
    for (int idx = tid; idx < KX * 24; idx += 256) {
        const int e = idx / 24, rem = idx - e * 24;
        const int hf = rem / 12, q = rem - hf * 12;
        float v = 0.f;
        if (q < 10) {
            const int m = (q & 3) + 8 * (q >> 2) + 4 * hf;
            const int h = (m & 3) + 4 * (m >> 3) + ((m & 4) ? 10 : 0);
            v = W2[e * DH + h];
        }
        s_w2[idx] = v;
    }
    if (tid < 64) {
        const int m = tid & 31, kb = (tid >> 5) * 8;
        BFU u;
#pragma unroll
        for (int j = 0; j < 8; ++j) {
            const int kk = kb + j;
            u.s[j] = f2bf(kk < DIN ? proto[m * DIN + kk] : 0.f);  // slot 10 = 0
        }
        s_pf[tid] = u.v;
    }
    if (tid < 32) {
        const int hf = tid >> 4, q = tid & 15;
        const int p = (q & 3) + 8 * (q >> 2) + 4 * hf;
        float s = 0.f;
#pragma unroll
        for (int i = 0; i < DIN; ++i) { const float v = proto[p * DIN + i]; s = fmaf(v, v, s); }
        s_pn2[tid] = s;
        s_b2c[tid] = b2[p];
    }
    __syncthreads();

    const int lane = tid & 63;
    const int wave = tid >> 6;
    const int half = lane >> 5;   // k-slice for A/B frags; C-half for epilogue
    const int col  = lane & 31;
    const bf16x8 pfrag = s_pf[lane];

    const int row = (blockIdx.x * 4 + wave) * 32 + col;
    const int rr = (row < B) ? row : (B - 1);

    // ---- B-frag: x_ext[rr][half*8 .. +7]; slot 10 = 1.0 (bias) ----
    float xe[8];
    const float* xr = x + (size_t)rr * DIN;
    if (half == 0) {
#pragma unroll
        for (int i = 0; i < 4; ++i) {
            const float2 v = *(const float2*)(xr + 2 * i);
            xe[2 * i] = v.x; xe[2 * i + 1] = v.y;
        }
    } else {
        const float2 v = *(const float2*)(xr + 8);
        xe[0] = v.x; xe[1] = v.y; xe[2] = 1.f;
        xe[3] = 0.f; xe[4] = 0.f; xe[5] = 0.f; xe[6] = 0.f; xe[7] = 0.f;
    }
    BFU xu;
#pragma unroll
    for (int j = 0; j < 8; ++j) xu.s[j] = f2bf(xe[j]);
    const bf16x8 xfrag = xu.v;

    // ||x||^2 (fp32): half0 sums its 8, half1 only x[8],x[9]
    float part;
    if (half == 0) {
        part = 0.f;
#pragma unroll
        for (int j = 0; j < 8; ++j) part = fmaf(xe[j], xe[j], part);
    } else {
        part = fmaf(xe[0], xe[0], xe[1] * xe[1]);
    }
    const float xn2 = part + __shfl_xor(part, 32);

    // ---- gating MFMA + gates; fold b2 terms here ----
    f32x16 zg = ZERO16;
    const f32x16 dotg = __builtin_amdgcn_mfma_f32_32x32x16_bf16(pfrag, xfrag, zg, 0, 0, 0);

    float gate[16], gx[16];
    float dsum = 0.f;
    float nsA = 0.f, nsB = 0.f;    // two relaxed numerator chains
    {
        const float* pn2h = s_pn2 + half * 16;
        const float* b2c  = s_b2c + half * 16;
#pragma unroll
        for (int q = 0; q < 16; ++q) {
            float d2 = fmaf(dotg[q], -2.f, xn2 + pn2h[q]);
            d2 = fmaxf(d2, 0.f);
            const float g = __expf(-__fsqrt_rn(d2));
            gate[q] = g;
            dsum += g;
            nsA = fmaf(g, b2c[q], nsA);
        }
#pragma unroll
        for (int q = 0; q < 16; ++q) gx[q] = __shfl_xor(gate[q], 32);
    }

    // ---- A-frag read index for this lane (compacted mapping) ----
    const int m = col;
    const bool mvalid = (m & 4) ? (m < 22) : (m < 18);
    const int hidx = (m & 3) + 4 * (m >> 3) + ((m & 4) ? 10 : 0);  // 0..19 when valid
    const int abase = half * 20 + (mvalid ? hidx : 0);

    // ---- expert loop: pairs (elo, elo+4); partials combined locally via gx ----
#pragma unroll 2
    for (int j = 0; j < 16; ++j) {
        const int elo = (j & 3) + 8 * (j >> 2);
        const int ehi = elo + 4;

        bf16x8 alo = {0, 0, 0, 0, 0, 0, 0, 0};
        bf16x8 ahi = {0, 0, 0, 0, 0, 0, 0, 0};
        if (mvalid) {
            alo = s_af[elo * 40 + abase];
            ahi = s_af[ehi * 40 + abase];
        }
        f32x16 z0 = ZERO16, z1 = ZERO16;
        const f32x16 clo = __builtin_amdgcn_mfma_f32_32x32x16_bf16(alo, xfrag, z0, 0, 0, 0);
        const f32x16 chi = __builtin_amdgcn_mfma_f32_32x32x16_bf16(ahi, xfrag, z1, 0, 0, 0);

        // epilogue touches only C-regs 0..11 (12-padded compacted layout)
        const float4* w4lo = (const float4*)(s_w2 + elo * 24 + half * 12);
        const float4* w4hi = (const float4*)(s_w2 + ehi * 24 + half * 12);
        v2f plov = v2f{0.f, 0.f}, phiv = v2f{0.f, 0.f};
#pragma unroll
        for (int i = 0; i < 3; ++i) {
            const float4 wl = w4lo[i];
            const float4 wh = w4hi[i];
            v2f cl0 = __builtin_elementwise_max(v2f{clo[4 * i + 0], clo[4 * i + 1]}, v2f{0.f, 0.f});
            v2f cl1 = __builtin_elementwise_max(v2f{clo[4 * i + 2], clo[4 * i + 3]}, v2f{0.f, 0.f});
            v2f ch0 = __builtin_elementwise_max(v2f{chi[4 * i + 0], chi[4 * i + 1]}, v2f{0.f, 0.f});
            v2f ch1 = __builtin_elementwise_max(v2f{chi[4 * i + 2], chi[4 * i + 3]}, v2f{0.f, 0.f});
            plov = __builtin_elementwise_fma(cl0, v2f{wl.x, wl.y}, plov);
            plov = __builtin_elementwise_fma(cl1, v2f{wl.z, wl.w}, plov);
            phiv = __builtin_elementwise_fma(ch0, v2f{wh.x, wh.y}, phiv);
            phiv = __builtin_elementwise_fma(ch1, v2f{wh.z, wh.w}, phiv);
        }
        const float pplo = plov.x + plov.y;
        const float pphi = phiv.x + phiv.y;

        // half0 lane: own expert = elo (partial pplo), other = ehi (pphi)
        // half1 lane: own expert = ehi (partial pphi), other = elo (pplo)
        const float p_own = half ? pphi : pplo;
        const float p_oth = half ? pplo : pphi;
        nsA = fmaf(gate[j], p_own, nsA);
        nsB = fmaf(gx[j],   p_oth, nsB);
    }

    // ---- cross-half combine & write ----
    float nsum = nsA + nsB;
    nsum += __shfl_xor(nsum, 32);
    dsum += __shfl_xor(dsum, 32);
    if (half == 0 && row < B) out[row] = nsum / dsum;
}

extern "C" void kernel_launch(void* const* d_in, const int* in_sizes, int n_in,
                              void* d_out, int out_size, void* d_ws, size_t ws_size,
                              hipStream_t stream) {
    const float* x     = (const float*)d_in[0];
    const float* W1    = (const float*)d_in[1];
    const float* b1    = (const float*)d_in[2];
    const float* W2    = (const float*)d_in[3];
    const float* b2    = (const float*)d_in[4];
    const float* proto = (const float*)d_in[5];
    float* out = (float*)d_out;

    const int B = out_size;            // D_OUT = 1
    const int rows_per_block = 4 * 32; // 4 waves x 1 tile x 32 rows
    const int grid = (B + rows_per_block - 1) / rows_per_block;
    hipLaunchKernelGGL(moe_kernel, dim3(grid), dim3(256), 0, stream,
                       x, W1, b1, W2, b2, proto, out, B);
}

// Round 12
// 96.900 us; speedup vs baseline: 9.6899x; 1.0514x over previous
//
#include <hip/hip_runtime.h>

// PiecewiseSparseMLP: B=262144 rows, K=32 experts (10 -> 20 -> 1), distance-softmax gating.
// Round 12: R11's compute body verbatim; packaging change only: block=512 (8 waves,
// 1 tile/wave), grid=1024. The 25 KB LDS tables are shared by 8 waves -> residency
// min(LDS:6, threads:4, VGPR@52:4) = 4 blocks/CU = 32 waves/CU (100% cap). Every
// 256-thread variant (R7/R10/R11) sat at 31-33% measured occupancy; block=512 rounds
// (R3/R5) measured 57-70%. launch_bounds(512,4) = cap 128, the proven no-spill point.

#define KX 32
#define DIN 10
#define DH 20
#define BLOCK 512
#define WPB 8   // waves per block

typedef short bf16x8 __attribute__((ext_vector_type(8)));
typedef float f32x16 __attribute__((ext_vector_type(16)));
typedef float v2f    __attribute__((ext_vector_type(2)));

#define ZERO16 {0.f,0.f,0.f,0.f, 0.f,0.f,0.f,0.f, 0.f,0.f,0.f,0.f, 0.f,0.f,0.f,0.f}

__device__ inline unsigned short f2bf(float f) {   // fp32 -> bf16 RNE
    unsigned int u = __float_as_uint(f);
    unsigned int r = u + 0x7fffu + ((u >> 16) & 1u);
    return (unsigned short)(r >> 16);
}

union BFU { bf16x8 v; unsigned short s[8]; };

__global__ __launch_bounds__(BLOCK, 4) void moe_kernel(
    const float* __restrict__ x,      // [B,10]
    const float* __restrict__ W1,     // [32,20,10]
    const float* __restrict__ b1,     // [32,20]
    const float* __restrict__ W2,     // [32,1,20]
    const float* __restrict__ b2,     // [32]
    const float* __restrict__ proto,  // [32,10]
    float* __restrict__ out,          // [B]
    int B)
{
    __shared__ bf16x8 s_af[KX * 40];   // A-frags: [e][kslice*20 + h] (20 KB)
    __shared__ float  s_w2[KX * 24];   // [e][half*12 + reg] W2 in compacted C-reg order (3 KB)
    __shared__ bf16x8 s_pf[64];        // proto A-frag (1 KB)
    __shared__ float  s_pn2[32];       // ||proto||^2 in [half*16+reg] order
    __shared__ float  s_b2c[32];       // b2 in [half*16+reg] order

    const int tid = threadIdx.x;

    // ---- build LDS tables (shared by all 8 waves) ----
    for (int idx = tid; idx < KX * 40; idx += BLOCK) {
        const int e = idx / 40, rem = idx - e * 40;
        const int ks = rem / 20, h = rem - ks * 20;   // k-slice, hidden index
        BFU u;
#pragma unroll
        for (int j = 0; j < 8; ++j) {
            const int kk = ks * 8 + j;
            float v = 0.f;
            if (kk < DIN) v = W1[(e * DH + h) * DIN + kk];
            else if (kk == DIN) v = b1[e * DH + h];   // bias slot (x_ext[10]=1)
            u.s[j] = f2bf(v);
        }
        s_af[idx] = u.v;
    }
    // W2 in compacted C-reg order: reg q of half hf -> m=(q&3)+8*(q>>2)+4*hf ->
    // h=(m&3)+4*(m>>3)+10*((m&4)?1:0); q=10,11 are pad (zero).
    for (int idx = tid; idx < KX * 24; idx += BLOCK) {
        const int e = idx / 24, rem = idx - e * 24;
        const int hf = rem / 12, q = rem - hf * 12;
        float v = 0.f;
        if (q < 10) {
            const int m = (q & 3) + 8 * (q >> 2) + 4 * hf;
            const int h = (m & 3) + 4 * (m >> 3) + ((m & 4) ? 10 : 0);
            v = W2[e * DH + h];
        }
        s_w2[idx] = v;
    }
    if (tid < 64) {
        const int m = tid & 31, kb = (tid >> 5) * 8;
        BFU u;
#pragma unroll
        for (int j = 0; j < 8; ++j) {
            const int kk = kb + j;
            u.s[j] = f2bf(kk < DIN ? proto[m * DIN + kk] : 0.f);  // slot 10 = 0
        }
        s_pf[tid] = u.v;
    }
    if (tid < 32) {
        const int hf = tid >> 4, q = tid & 15;
        const int p = (q & 3) + 8 * (q >> 2) + 4 * hf;
        float s = 0.f;
#pragma unroll
        for (int i = 0; i < DIN; ++i) { const float v = proto[p * DIN + i]; s = fmaf(v, v, s); }
        s_pn2[tid] = s;
        s_b2c[tid] = b2[p];
    }
    __syncthreads();

    const int lane = tid & 63;
    const int wave = tid >> 6;
    const int half = lane >> 5;   // k-slice for A/B frags; C-half for epilogue
    const int col  = lane & 31;
    const bf16x8 pfrag = s_pf[lane];

    const int row = (blockIdx.x * WPB + wave) * 32 + col;
    const int rr = (row < B) ? row : (B - 1);

    // ---- B-frag: x_ext[rr][half*8 .. +7]; slot 10 = 1.0 (bias) ----
    float xe[8];
    const float* xr = x + (size_t)rr * DIN;
    if (half == 0) {
#pragma unroll
        for (int i = 0; i < 4; ++i) {
            const float2 v = *(const float2*)(xr + 2 * i);
            xe[2 * i] = v.x; xe[2 * i + 1] = v.y;
        }
    } else {
        const float2 v = *(const float2*)(xr + 8);
        xe[0] = v.x; xe[1] = v.y; xe[2] = 1.f;
        xe[3] = 0.f; xe[4] = 0.f; xe[5] = 0.f; xe[6] = 0.f; xe[7] = 0.f;
    }
    BFU xu;
#pragma unroll
    for (int j = 0; j < 8; ++j) xu.s[j] = f2bf(xe[j]);
    const bf16x8 xfrag = xu.v;

    // ||x||^2 (fp32): half0 sums its 8, half1 only x[8],x[9]
    float part;
    if (half == 0) {
        part = 0.f;
#pragma unroll
        for (int j = 0; j < 8; ++j) part = fmaf(xe[j], xe[j], part);
    } else {
        part = fmaf(xe[0], xe[0], xe[1] * xe[1]);
    }
    const float xn2 = part + __shfl_xor(part, 32);

    // ---- gating MFMA + gates; fold b2 terms here ----
    f32x16 zg = ZERO16;
    const f32x16 dotg = __builtin_amdgcn_mfma_f32_32x32x16_bf16(pfrag, xfrag, zg, 0, 0, 0);

    float gate[16], gx[16];
    float dsum = 0.f;
    float nsA = 0.f, nsB = 0.f;    // two relaxed numerator chains
    {
        const float* pn2h = s_pn2 + half * 16;
        const float* b2c  = s_b2c + half * 16;
#pragma unroll
        for (int q = 0; q < 16; ++q) {
            float d2 = fmaf(dotg[q], -2.f, xn2 + pn2h[q]);
            d2 = fmaxf(d2, 0.f);
            const float g = __expf(-__fsqrt_rn(d2));
            gate[q] = g;
            dsum += g;
            nsA = fmaf(g, b2c[q], nsA);
        }
#pragma unroll
        for (int q = 0; q < 16; ++q) gx[q] = __shfl_xor(gate[q], 32);
    }

    // ---- A-frag read index for this lane (compacted mapping) ----
    const int m = col;
    const bool mvalid = (m & 4) ? (m < 22) : (m < 18);
    const int hidx = (m & 3) + 4 * (m >> 3) + ((m & 4) ? 10 : 0);  // 0..19 when valid
    const int abase = half * 20 + (mvalid ? hidx : 0);

    // ---- expert loop: pairs (elo, elo+4); partials combined locally via gx ----
#pragma unroll 2
    for (int j = 0; j < 16; ++j) {
        const int elo = (j & 3) + 8 * (j >> 2);
        const int ehi = elo + 4;

        bf16x8 alo = {0, 0, 0, 0, 0, 0, 0, 0};
        bf16x8 ahi = {0, 0, 0, 0, 0, 0, 0, 0};
        if (mvalid) {
            alo = s_af[elo * 40 + abase];
            ahi = s_af[ehi * 40 + abase];
        }
        f32x16 z0 = ZERO16, z1 = ZERO16;
        const f32x16 clo = __builtin_amdgcn_mfma_f32_32x32x16_bf16(alo, xfrag, z0, 0, 0, 0);
        const f32x16 chi = __builtin_amdgcn_mfma_f32_32x32x16_bf16(ahi, xfrag, z1, 0, 0, 0);

        // epilogue touches only C-regs 0..11 (12-padded compacted layout)
        const float4* w4lo = (const float4*)(s_w2 + elo * 24 + half * 12);
        const float4* w4hi = (const float4*)(s_w2 + ehi * 24 + half * 12);
        v2f plov = v2f{0.f, 0.f}, phiv = v2f{0.f, 0.f};
#pragma unroll
        for (int i = 0; i < 3; ++i) {
            const float4 wl = w4lo[i];
            const float4 wh = w4hi[i];
            v2f cl0 = __builtin_elementwise_max(v2f{clo[4 * i + 0], clo[4 * i + 1]}, v2f{0.f, 0.f});
            v2f cl1 = __builtin_elementwise_max(v2f{clo[4 * i + 2], clo[4 * i + 3]}, v2f{0.f, 0.f});
            v2f ch0 = __builtin_elementwise_max(v2f{chi[4 * i + 0], chi[4 * i + 1]}, v2f{0.f, 0.f});
            v2f ch1 = __builtin_elementwise_max(v2f{chi[4 * i + 2], chi[4 * i + 3]}, v2f{0.f, 0.f});
            plov = __builtin_elementwise_fma(cl0, v2f{wl.x, wl.y}, plov);
            plov = __builtin_elementwise_fma(cl1, v2f{wl.z, wl.w}, plov);
            phiv = __builtin_elementwise_fma(ch0, v2f{wh.x, wh.y}, phiv);
            phiv = __builtin_elementwise_fma(ch1, v2f{wh.z, wh.w}, phiv);
        }
        const float pplo = plov.x + plov.y;
        const float pphi = phiv.x + phiv.y;

        // half0 lane: own expert = elo (partial pplo), other = ehi (pphi)
        // half1 lane: own expert = ehi (partial pphi), other = elo (pplo)
        const float p_own = half ? pphi : pplo;
        const float p_oth = half ? pplo : pphi;
        nsA = fmaf(gate[j], p_own, nsA);
        nsB = fmaf(gx[j],   p_oth, nsB);
    }

    // ---- cross-half combine & write ----
    float nsum = nsA + nsB;
    nsum += __shfl_xor(nsum, 32);
    dsum += __shfl_xor(dsum, 32);
    if (half == 0 && row < B) out[row] = nsum / dsum;
}

extern "C" void kernel_launch(void* const* d_in, const int* in_sizes, int n_in,
                              void* d_out, int out_size, void* d_ws, size_t ws_size,
                              hipStream_t stream) {
    const float* x     = (const float*)d_in[0];
    const float* W1    = (const float*)d_in[1];
    const float* b1    = (const float*)d_in[2];
    const float* W2    = (const float*)d_in[3];
    const float* b2    = (const float*)d_in[4];
    const float* proto = (const float*)d_in[5];
    float* out = (float*)d_out;

    const int B = out_size;              // D_OUT = 1
    const int rows_per_block = WPB * 32; // 8 waves x 32 rows = 256
    const int grid = (B + rows_per_block - 1) / rows_per_block;
    hipLaunchKernelGGL(moe_kernel, dim3(grid), dim3(BLOCK), 0, stream,
                       x, W1, b1, W2, b2, proto, out, B);
}

// Round 13
// 96.736 us; speedup vs baseline: 9.7063x; 1.0017x over previous
//
#include <hip/hip_runtime.h>

// PiecewiseSparseMLP: B=262144 rows, K=32 experts (10 -> 20 -> 1), distance-softmax gating.
// Round 13: R12 body + two cuts:
//  (1) single hoisted kZero accumulator passed to ALL 33 MFMAs (per-MFMA ZERO16
//      rematerialization suspected ~500 v_mov/tile — m97 disasm precedent);
//  (2) 2 tiles/wave sequential (grid=512): halves per-CU staging + launch overhead,
//      register liveness unchanged vs R12 (tile completes before next starts).
// Proven-stable pattern kept: block=512, launch_bounds(512,4) (cap 128, no-spill point),
// expert loop `unroll 2`, compacted C-reg epilogue, gx pre-exchange + b2 fold.

#define KX 32
#define DIN 10
#define DH 20
#define BLOCK 512
#define WPB 8   // waves per block
#define TPW 2   // tiles per wave

typedef short bf16x8 __attribute__((ext_vector_type(8)));
typedef float f32x16 __attribute__((ext_vector_type(16)));
typedef float v2f    __attribute__((ext_vector_type(2)));

#define ZERO16 {0.f,0.f,0.f,0.f, 0.f,0.f,0.f,0.f, 0.f,0.f,0.f,0.f, 0.f,0.f,0.f,0.f}

__device__ inline unsigned short f2bf(float f) {   // fp32 -> bf16 RNE
    unsigned int u = __float_as_uint(f);
    unsigned int r = u + 0x7fffu + ((u >> 16) & 1u);
    return (unsigned short)(r >> 16);
}

union BFU { bf16x8 v; unsigned short s[8]; };

__global__ __launch_bounds__(BLOCK, 4) void moe_kernel(
    const float* __restrict__ x,      // [B,10]
    const float* __restrict__ W1,     // [32,20,10]
    const float* __restrict__ b1,     // [32,20]
    const float* __restrict__ W2,     // [32,1,20]
    const float* __restrict__ b2,     // [32]
    const float* __restrict__ proto,  // [32,10]
    float* __restrict__ out,          // [B]
    int B)
{
    __shared__ bf16x8 s_af[KX * 40];   // A-frags: [e][kslice*20 + h] (20 KB)
    __shared__ float  s_w2[KX * 24];   // [e][half*12 + reg] W2 compacted C-reg order (3 KB)
    __shared__ bf16x8 s_pf[64];        // proto A-frag (1 KB)
    __shared__ float  s_pn2[32];       // ||proto||^2 in [half*16+reg] order
    __shared__ float  s_b2c[32];       // b2 in [half*16+reg] order

    const int tid = threadIdx.x;

    // ---- build LDS tables (shared by all 8 waves, amortized over 2 tiles/wave) ----
    for (int idx = tid; idx < KX * 40; idx += BLOCK) {
        const int e = idx / 40, rem = idx - e * 40;
        const int ks = rem / 20, h = rem - ks * 20;   // k-slice, hidden index
        BFU u;
#pragma unroll
        for (int j = 0; j < 8; ++j) {
            const int kk = ks * 8 + j;
            float v = 0.f;
            if (kk < DIN) v = W1[(e * DH + h) * DIN + kk];
            else if (kk == DIN) v = b1[e * DH + h];   // bias slot (x_ext[10]=1)
            u.s[j] = f2bf(v);
        }
        s_af[idx] = u.v;
    }
    // W2 in compacted C-reg order: reg q of half hf -> m=(q&3)+8*(q>>2)+4*hf ->
    // h=(m&3)+4*(m>>3)+10*((m&4)?1:0); q=10,11 pad (zero).
    for (int idx = tid; idx < KX * 24; idx += BLOCK) {
        const int e = idx / 24, rem = idx - e * 24;
        const int hf = rem / 12, q = rem - hf * 12;
        float v = 0.f;
        if (q < 10) {
            const int m = (q & 3) + 8 * (q >> 2) + 4 * hf;
            const int h = (m & 3) + 4 * (m >> 3) + ((m & 4) ? 10 : 0);
            v = W2[e * DH + h];
        }
        s_w2[idx] = v;
    }
    if (tid < 64) {
        const int m = tid & 31, kb = (tid >> 5) * 8;
        BFU u;
#pragma unroll
        for (int j = 0; j < 8; ++j) {
            const int kk = kb + j;
            u.s[j] = f2bf(kk < DIN ? proto[m * DIN + kk] : 0.f);  // slot 10 = 0
        }
        s_pf[tid] = u.v;
    }
    if (tid < 32) {
        const int hf = tid >> 4, q = tid & 15;
        const int p = (q & 3) + 8 * (q >> 2) + 4 * hf;
        float s = 0.f;
#pragma unroll
        for (int i = 0; i < DIN; ++i) { const float v = proto[p * DIN + i]; s = fmaf(v, v, s); }
        s_pn2[tid] = s;
        s_b2c[tid] = b2[p];
    }
    __syncthreads();

    const int lane = tid & 63;
    const int wave = tid >> 6;
    const int half = lane >> 5;   // k-slice for A/B frags; C-half for epilogue
    const int col  = lane & 31;
    const bf16x8 pfrag = s_pf[lane];

    // single hoisted zero accumulator for ALL MFMAs
    const f32x16 kZero = ZERO16;

    // A-frag read index for this lane (compacted mapping) — tile-invariant
    const int m = col;
    const bool mvalid = (m & 4) ? (m < 22) : (m < 18);
    const int hidx = (m & 3) + 4 * (m >> 3) + ((m & 4) ? 10 : 0);  // 0..19 when valid
    const int abase = half * 20 + (mvalid ? hidx : 0);

#pragma unroll 1
    for (int t = 0; t < TPW; ++t) {
        const int row = ((blockIdx.x * WPB + wave) * TPW + t) * 32 + col;
        const int rr = (row < B) ? row : (B - 1);

        // ---- B-frag: x_ext[rr][half*8 .. +7]; slot 10 = 1.0 (bias) ----
        float xe[8];
        const float* xr = x + (size_t)rr * DIN;
        if (half == 0) {
#pragma unroll
            for (int i = 0; i < 4; ++i) {
                const float2 v = *(const float2*)(xr + 2 * i);
                xe[2 * i] = v.x; xe[2 * i + 1] = v.y;
            }
        } else {
            const float2 v = *(const float2*)(xr + 8);
            xe[0] = v.x; xe[1] = v.y; xe[2] = 1.f;
            xe[3] = 0.f; xe[4] = 0.f; xe[5] = 0.f; xe[6] = 0.f; xe[7] = 0.f;
        }
        BFU xu;
#pragma unroll
        for (int j = 0; j < 8; ++j) xu.s[j] = f2bf(xe[j]);
        const bf16x8 xfrag = xu.v;

        // ||x||^2 (fp32): half0 sums its 8, half1 only x[8],x[9]
        float part;
        if (half == 0) {
            part = 0.f;
#pragma unroll
            for (int j = 0; j < 8; ++j) part = fmaf(xe[j], xe[j], part);
        } else {
            part = fmaf(xe[0], xe[0], xe[1] * xe[1]);
        }
        const float xn2 = part + __shfl_xor(part, 32);

        // ---- gating MFMA + gates; fold b2 terms here ----
        const f32x16 dotg = __builtin_amdgcn_mfma_f32_32x32x16_bf16(pfrag, xfrag, kZero, 0, 0, 0);

        float gate[16], gx[16];
        float dsum = 0.f;
        float nsA = 0.f, nsB = 0.f;    // two relaxed numerator chains
        {
            const float* pn2h = s_pn2 + half * 16;
            const float* b2c  = s_b2c + half * 16;
#pragma unroll
            for (int q = 0; q < 16; ++q) {
                float d2 = fmaf(dotg[q], -2.f, xn2 + pn2h[q]);
                d2 = fmaxf(d2, 0.f);
                const float g = __expf(-__fsqrt_rn(d2));
                gate[q] = g;
                dsum += g;
                nsA = fmaf(g, b2c[q], nsA);
            }
#pragma unroll
            for (int q = 0; q < 16; ++q) gx[q] = __shfl_xor(gate[q], 32);
        }

        // ---- expert loop: pairs (elo, elo+4); partials combined locally via gx ----
#pragma unroll 2
        for (int j = 0; j < 16; ++j) {
            const int elo = (j & 3) + 8 * (j >> 2);
            const int ehi = elo + 4;

            bf16x8 alo = {0, 0, 0, 0, 0, 0, 0, 0};
            bf16x8 ahi = {0, 0, 0, 0, 0, 0, 0, 0};
            if (mvalid) {
                alo = s_af[elo * 40 + abase];
                ahi = s_af[ehi * 40 + abase];
            }
            const f32x16 clo = __builtin_amdgcn_mfma_f32_32x32x16_bf16(alo, xfrag, kZero, 0, 0, 0);
            const f32x16 chi = __builtin_amdgcn_mfma_f32_32x32x16_bf16(ahi, xfrag, kZero, 0, 0, 0);

            // epilogue touches only C-regs 0..11 (12-padded compacted layout)
            const float4* w4lo = (const float4*)(s_w2 + elo * 24 + half * 12);
            const float4* w4hi = (const float4*)(s_w2 + ehi * 24 + half * 12);
            v2f plov = v2f{0.f, 0.f}, phiv = v2f{0.f, 0.f};
#pragma unroll
            for (int i = 0; i < 3; ++i) {
                const float4 wl = w4lo[i];
                const float4 wh = w4hi[i];
                v2f cl0 = __builtin_elementwise_max(v2f{clo[4 * i + 0], clo[4 * i + 1]}, v2f{0.f, 0.f});
                v2f cl1 = __builtin_elementwise_max(v2f{clo[4 * i + 2], clo[4 * i + 3]}, v2f{0.f, 0.f});
                v2f ch0 = __builtin_elementwise_max(v2f{chi[4 * i + 0], chi[4 * i + 1]}, v2f{0.f, 0.f});
                v2f ch1 = __builtin_elementwise_max(v2f{chi[4 * i + 2], chi[4 * i + 3]}, v2f{0.f, 0.f});
                plov = __builtin_elementwise_fma(cl0, v2f{wl.x, wl.y}, plov);
                plov = __builtin_elementwise_fma(cl1, v2f{wl.z, wl.w}, plov);
                phiv = __builtin_elementwise_fma(ch0, v2f{wh.x, wh.y}, phiv);
                phiv = __builtin_elementwise_fma(ch1, v2f{wh.z, wh.w}, phiv);
            }
            const float pplo = plov.x + plov.y;
            const float pphi = phiv.x + phiv.y;

            // half0 lane: own expert = elo (partial pplo), other = ehi (pphi)
            // half1 lane: own expert = ehi (partial pphi), other = elo (pplo)
            const float p_own = half ? pphi : pplo;
            const float p_oth = half ? pplo : pphi;
            nsA = fmaf(gate[j], p_own, nsA);
            nsB = fmaf(gx[j],   p_oth, nsB);
        }

        // ---- cross-half combine & write ----
        float nsum = nsA + nsB;
        nsum += __shfl_xor(nsum, 32);
        dsum += __shfl_xor(dsum, 32);
        if (half == 0 && row < B) out[row] = nsum / dsum;
    }
}

extern "C" void kernel_launch(void* const* d_in, const int* in_sizes, int n_in,
                              void* d_out, int out_size, void* d_ws, size_t ws_size,
                              hipStream_t stream) {
    const float* x     = (const float*)d_in[0];
    const float* W1    = (const float*)d_in[1];
    const float* b1    = (const float*)d_in[2];
    const float* W2    = (const float*)d_in[3];
    const float* b2    = (const float*)d_in[4];
    const float* proto = (const float*)d_in[5];
    float* out = (float*)d_out;

    const int B = out_size;                    // D_OUT = 1
    const int rows_per_block = WPB * TPW * 32; // 8 waves x 2 tiles x 32 rows = 512
    const int grid = (B + rows_per_block - 1) / rows_per_block;
    hipLaunchKernelGGL(moe_kernel, dim3(grid), dim3(BLOCK), 0, stream,
                       x, W1, b1, W2, b2, proto, out, B);
}

// Round 14
// 94.912 us; speedup vs baseline: 9.8928x; 1.0192x over previous
//
#include <hip/hip_runtime.h>

// PiecewiseSparseMLP: B=262144 rows, K=32 experts (10 -> 20 -> 1), distance-softmax gating.
// Round 14: 2 row-tiles INTERLEAVED in the expert-pair loop (64 rows/wave): each pair's
// 2 A-frag + 6 w2 ds_read_b128 serve 4 MFMAs and 2 epilogues (~40% LDS-issue cut; R11
// arithmetic showed VALU ~61% and LDS pipe ~60% both sub-saturated = chained-latency mix).
// To fund gate[2][16] (32 VGPRs), gx pre-exchange dropped -> R7-style per-pair partial
// shuffles (4 swizzles/pair, cheap on the freed LDS pipe). All arrays statically indexed
// (R8 lesson); block=512, launch_bounds(512,4)=cap 128 (proven no-spill); grid=512.

#define KX 32
#define DIN 10
#define DH 20
#define BLOCK 512
#define WPB 8   // waves per block
#define TPW 2   // row-tiles per wave (interleaved)

typedef short bf16x8 __attribute__((ext_vector_type(8)));
typedef float f32x16 __attribute__((ext_vector_type(16)));
typedef float v2f    __attribute__((ext_vector_type(2)));

#define ZERO16 {0.f,0.f,0.f,0.f, 0.f,0.f,0.f,0.f, 0.f,0.f,0.f,0.f, 0.f,0.f,0.f,0.f}

__device__ inline unsigned short f2bf(float f) {   // fp32 -> bf16 RNE
    unsigned int u = __float_as_uint(f);
    unsigned int r = u + 0x7fffu + ((u >> 16) & 1u);
    return (unsigned short)(r >> 16);
}

union BFU { bf16x8 v; unsigned short s[8]; };

__global__ __launch_bounds__(BLOCK, 4) void moe_kernel(
    const float* __restrict__ x,      // [B,10]
    const float* __restrict__ W1,     // [32,20,10]
    const float* __restrict__ b1,     // [32,20]
    const float* __restrict__ W2,     // [32,1,20]
    const float* __restrict__ b2,     // [32]
    const float* __restrict__ proto,  // [32,10]
    float* __restrict__ out,          // [B]
    int B)
{
    __shared__ bf16x8 s_af[KX * 40];   // A-frags: [e][kslice*20 + h] (20 KB)
    __shared__ float  s_w2[KX * 24];   // [e][half*12 + reg] W2 compacted C-reg order (3 KB)
    __shared__ bf16x8 s_pf[64];        // proto A-frag (1 KB)
    __shared__ float  s_pn2[32];       // ||proto||^2 in [half*16+reg] order

    const int tid = threadIdx.x;

    // ---- build LDS tables (shared by all 8 waves, amortized over 2 tiles/wave) ----
    for (int idx = tid; idx < KX * 40; idx += BLOCK) {
        const int e = idx / 40, rem = idx - e * 40;
        const int ks = rem / 20, h = rem - ks * 20;   // k-slice, hidden index
        BFU u;
#pragma unroll
        for (int j = 0; j < 8; ++j) {
            const int kk = ks * 8 + j;
            float v = 0.f;
            if (kk < DIN) v = W1[(e * DH + h) * DIN + kk];
            else if (kk == DIN) v = b1[e * DH + h];   // bias slot (x_ext[10]=1)
            u.s[j] = f2bf(v);
        }
        s_af[idx] = u.v;
    }
    // W2 in compacted C-reg order: reg q of half hf -> m=(q&3)+8*(q>>2)+4*hf ->
    // h=(m&3)+4*(m>>3)+10*((m&4)?1:0); q=10,11 pad (zero).
    for (int idx = tid; idx < KX * 24; idx += BLOCK) {
        const int e = idx / 24, rem = idx - e * 24;
        const int hf = rem / 12, q = rem - hf * 12;
        float v = 0.f;
        if (q < 10) {
            const int m = (q & 3) + 8 * (q >> 2) + 4 * hf;
            const int h = (m & 3) + 4 * (m >> 3) + ((m & 4) ? 10 : 0);
            v = W2[e * DH + h];
        }
        s_w2[idx] = v;
    }
    if (tid < 64) {
        const int m = tid & 31, kb = (tid >> 5) * 8;
        BFU u;
#pragma unroll
        for (int j = 0; j < 8; ++j) {
            const int kk = kb + j;
            u.s[j] = f2bf(kk < DIN ? proto[m * DIN + kk] : 0.f);  // slot 10 = 0
        }
        s_pf[tid] = u.v;
    }
    if (tid < 32) {
        const int hf = tid >> 4, q = tid & 15;
        const int p = (q & 3) + 8 * (q >> 2) + 4 * hf;
        float s = 0.f;
#pragma unroll
        for (int i = 0; i < DIN; ++i) { const float v = proto[p * DIN + i]; s = fmaf(v, v, s); }
        s_pn2[tid] = s;
    }
    __syncthreads();

    const int lane = tid & 63;
    const int wave = tid >> 6;
    const int half = lane >> 5;   // k-slice for A/B frags; C-half for epilogue
    const int col  = lane & 31;
    const bf16x8 pfrag = s_pf[lane];
    const f32x16 kZero = ZERO16;

    // A-frag read index for this lane (compacted mapping) — tile-invariant
    const int m = col;
    const bool mvalid = (m & 4) ? (m < 22) : (m < 18);
    const int hidx = (m & 3) + 4 * (m >> 3) + ((m & 4) ? 10 : 0);  // 0..19 when valid
    const int abase = half * 20 + (mvalid ? hidx : 0);

    // ---- per-tile state (statically indexed only) ----
    int   row[TPW];
    bf16x8 xfrag[TPW];
    float gate[TPW][16];
    float nsum[TPW], dsum[TPW];

#pragma unroll
    for (int t = 0; t < TPW; ++t) {
        row[t] = ((blockIdx.x * WPB + wave) * TPW + t) * 32 + col;
        const int rr = (row[t] < B) ? row[t] : (B - 1);

        // B-frag: x_ext[rr][half*8 .. +7]; slot 10 = 1.0 (bias)
        float xe[8];
        const float* xr = x + (size_t)rr * DIN;
        if (half == 0) {
#pragma unroll
            for (int i = 0; i < 4; ++i) {
                const float2 v = *(const float2*)(xr + 2 * i);
                xe[2 * i] = v.x; xe[2 * i + 1] = v.y;
            }
        } else {
            const float2 v = *(const float2*)(xr + 8);
            xe[0] = v.x; xe[1] = v.y; xe[2] = 1.f;
            xe[3] = 0.f; xe[4] = 0.f; xe[5] = 0.f; xe[6] = 0.f; xe[7] = 0.f;
        }
        BFU xu;
#pragma unroll
        for (int j = 0; j < 8; ++j) xu.s[j] = f2bf(xe[j]);
        xfrag[t] = xu.v;

        // ||x||^2 (fp32): half0 sums its 8, half1 only x[8],x[9]
        float part;
        if (half == 0) {
            part = 0.f;
#pragma unroll
            for (int j = 0; j < 8; ++j) part = fmaf(xe[j], xe[j], part);
        } else {
            part = fmaf(xe[0], xe[0], xe[1] * xe[1]);
        }
        const float xn2 = part + __shfl_xor(part, 32);

        // gating MFMA + gates
        const f32x16 dotg = __builtin_amdgcn_mfma_f32_32x32x16_bf16(pfrag, xfrag[t], kZero, 0, 0, 0);
        const float* pn2h = s_pn2 + half * 16;
        float ds = 0.f;
#pragma unroll
        for (int q = 0; q < 16; ++q) {
            float d2 = fmaf(dotg[q], -2.f, xn2 + pn2h[q]);
            d2 = fmaxf(d2, 0.f);
            const float g = __expf(-__fsqrt_rn(d2));
            gate[t][q] = g;
            ds += g;
        }
        dsum[t] = ds;
        nsum[t] = 0.f;
    }

    // ---- expert loop: pairs (elo, elo+4); A-frag + w2 reads shared by both tiles ----
#pragma unroll 2
    for (int j = 0; j < 16; ++j) {
        const int elo = (j & 3) + 8 * (j >> 2);
        const int ehi = elo + 4;

        bf16x8 alo = {0, 0, 0, 0, 0, 0, 0, 0};
        bf16x8 ahi = {0, 0, 0, 0, 0, 0, 0, 0};
        if (mvalid) {
            alo = s_af[elo * 40 + abase];
            ahi = s_af[ehi * 40 + abase];
        }
        const float4* w4lo = (const float4*)(s_w2 + elo * 24 + half * 12);
        const float4* w4hi = (const float4*)(s_w2 + ehi * 24 + half * 12);
        const float4 wl0 = w4lo[0], wl1 = w4lo[1], wl2 = w4lo[2];
        const float4 wh0 = w4hi[0], wh1 = w4hi[1], wh2 = w4hi[2];

#pragma unroll
        for (int t = 0; t < TPW; ++t) {
            const f32x16 clo = __builtin_amdgcn_mfma_f32_32x32x16_bf16(alo, xfrag[t], kZero, 0, 0, 0);
            const f32x16 chi = __builtin_amdgcn_mfma_f32_32x32x16_bf16(ahi, xfrag[t], kZero, 0, 0, 0);

            v2f plov = v2f{0.f, 0.f}, phiv = v2f{0.f, 0.f};
            {
                v2f c;
                c = __builtin_elementwise_max(v2f{clo[0],  clo[1]},  v2f{0.f, 0.f});
                plov = __builtin_elementwise_fma(c, v2f{wl0.x, wl0.y}, plov);
                c = __builtin_elementwise_max(v2f{clo[2],  clo[3]},  v2f{0.f, 0.f});
                plov = __builtin_elementwise_fma(c, v2f{wl0.z, wl0.w}, plov);
                c = __builtin_elementwise_max(v2f{clo[4],  clo[5]},  v2f{0.f, 0.f});
                plov = __builtin_elementwise_fma(c, v2f{wl1.x, wl1.y}, plov);
                c = __builtin_elementwise_max(v2f{clo[6],  clo[7]},  v2f{0.f, 0.f});
                plov = __builtin_elementwise_fma(c, v2f{wl1.z, wl1.w}, plov);
                c = __builtin_elementwise_max(v2f{clo[8],  clo[9]},  v2f{0.f, 0.f});
                plov = __builtin_elementwise_fma(c, v2f{wl2.x, wl2.y}, plov);
                c = __builtin_elementwise_max(v2f{clo[10], clo[11]}, v2f{0.f, 0.f});
                plov = __builtin_elementwise_fma(c, v2f{wl2.z, wl2.w}, plov);

                c = __builtin_elementwise_max(v2f{chi[0],  chi[1]},  v2f{0.f, 0.f});
                phiv = __builtin_elementwise_fma(c, v2f{wh0.x, wh0.y}, phiv);
                c = __builtin_elementwise_max(v2f{chi[2],  chi[3]},  v2f{0.f, 0.f});
                phiv = __builtin_elementwise_fma(c, v2f{wh0.z, wh0.w}, phiv);
                c = __builtin_elementwise_max(v2f{chi[4],  chi[5]},  v2f{0.f, 0.f});
                phiv = __builtin_elementwise_fma(c, v2f{wh1.x, wh1.y}, phiv);
                c = __builtin_elementwise_max(v2f{chi[6],  chi[7]},  v2f{0.f, 0.f});
                phiv = __builtin_elementwise_fma(c, v2f{wh1.z, wh1.w}, phiv);
                c = __builtin_elementwise_max(v2f{chi[8],  chi[9]},  v2f{0.f, 0.f});
                phiv = __builtin_elementwise_fma(c, v2f{wh2.x, wh2.y}, phiv);
                c = __builtin_elementwise_max(v2f{chi[10], chi[11]}, v2f{0.f, 0.f});
                phiv = __builtin_elementwise_fma(c, v2f{wh2.z, wh2.w}, phiv);
            }
            const float pplo = plov.x + plov.y;
            const float pphi = phiv.x + phiv.y;
            const float plo = pplo + __shfl_xor(pplo, 32);
            const float phi = pphi + __shfl_xor(pphi, 32);
            const float pred = half ? (phi + b2[ehi]) : (plo + b2[elo]);
            nsum[t] = fmaf(gate[t][j], pred, nsum[t]);
        }
    }

    // ---- cross-half combine & write (both tiles) ----
#pragma unroll
    for (int t = 0; t < TPW; ++t) {
        float ns = nsum[t] + __shfl_xor(nsum[t], 32);
        float ds = dsum[t] + __shfl_xor(dsum[t], 32);
        if (half == 0 && row[t] < B) out[row[t]] = ns / ds;
    }
}

extern "C" void kernel_launch(void* const* d_in, const int* in_sizes, int n_in,
                              void* d_out, int out_size, void* d_ws, size_t ws_size,
                              hipStream_t stream) {
    const float* x     = (const float*)d_in[0];
    const float* W1    = (const float*)d_in[1];
    const float* b1    = (const float*)d_in[2];
    const float* W2    = (const float*)d_in[3];
    const float* b2    = (const float*)d_in[4];
    const float* proto = (const float*)d_in[5];
    float* out = (float*)d_out;

    const int B = out_size;                    // D_OUT = 1
    const int rows_per_block = WPB * TPW * 32; // 8 waves x 2 tiles x 32 rows = 512
    const int grid = (B + rows_per_block - 1) / rows_per_block;
    hipLaunchKernelGGL(moe_kernel, dim3(grid), dim3(BLOCK), 0, stream,
                       x, W1, b1, W2, b2, proto, out, B);
}